// Round 6
// baseline (113.357 us; speedup 1.0000x reference)
//
#include <hip/hip_runtime.h>
#include <hip/hip_fp16.h>

// Problem constants (from reference)
#define SPP   16
#define SH    256
#define SW    256
#define HI    1024
#define WI    1024
#define CH    3
#define BATCH 4

// Tile geometry: 16x4 sensor px per block.
// Warped bbox at t=1: x-span 16 steps * 5.25 px/step = 84 (+4 margin) = 88;
// y-span 4 steps * 5.25 = 21 (+4) = 25. LDS capacity: 26 rows x 92 cols.
#define TSX   16
#define TSY   4
#define MAXW  92
#define MAXH  26

// tanh via v_exp_f32; |arg| <= ~1.2 here, abs error ~1e-6 (threshold 1.7e-2).
__device__ __forceinline__ float fast_tanh(float x) {
    const float e = __expf(2.0f * x);
    return (e - 1.0f) * __builtin_amdgcn_rcpf(e + 1.0f);
}

// Block = one 16x4 sensor tile, ALL 4 batches (batch loop inside; geometry
// registers persist). Threads: lane bits 0-3 = px-x, bits 4-5 = spp quarter,
// bits 6-7 = px-y. Each thread: 4 spp geometries once, then per batch stage
// bbox -> LDS (fp16 NHWC4) and sample from LDS. spp quarters reduced by
// __shfl_xor 16,32 (within-wave).
//
// Border algebra: xb = min(floor(gx), W-2), fx = gx - xb (reaches 1.0 at the
// border) — identical to the reference's clamp.
__global__ __launch_bounds__(256) void foveated_tile4(
    const float* __restrict__ img,
    const float* __restrict__ t_ptr,
    const float* __restrict__ jitter,
    float* __restrict__ out)
{
    __shared__ uint2 lds[MAXH * MAXW];   // 19136 B -> 4+ blocks/CU

    // 1024 blocks = 16 tx * 64 ty. XCD stripe: each XCD's 128 blocks span the
    // full ty range (center + edge tiles) -> balanced foveal load.
    const int bid = blockIdx.x;
    const int L   = (bid & 7) * 128 + (bid >> 3);
    const int ty  = L & 63;
    const int tx  = L >> 6;

    const int th = threadIdx.x;
    const int lx = th & 15;          // px-x within tile
    const int q  = (th >> 4) & 3;    // spp quarter (4 spp each)
    const int ly = th >> 6;          // px-y within tile

    const int sx = tx * TSX + lx;
    const int sy = ty * TSY + ly;

    const float step  = 2.0f / 256.0f;
    const float tt    = t_ptr[0];
    const float inv_s = __builtin_amdgcn_rcpf(fast_tanh(tt));

    // ---- uniform bbox of the tile's warped footprint (warp is monotone) ----
    auto gmap = [&](float p) {
        float g = (fast_tanh(tt * p) * inv_s + 1.0f) * 512.0f - 0.5f;
        return fminf(fmaxf(g, 0.0f), 1023.0f);
    };
    const float pxmin = -1.0f + (tx * TSX) * step, pxmax = pxmin + TSX * step;
    const float pymin = -1.0f + (ty * TSY) * step, pymax = pymin + TSY * step;
    const int x_lo = max((int)gmap(pxmin) - 1, 0);
    const int x_hi = min((int)gmap(pxmax) + 2, WI - 1);
    const int y_lo = max((int)gmap(pymin) - 1, 0);
    const int y_hi = min((int)gmap(pymax) + 2, HI - 1);
    const int ncols = x_hi - x_lo + 1;
    const int nrows = y_hi - y_lo + 1;
    const bool fits = (ncols <= MAXW) && (nrows <= MAXH);  // true at t=1

    // ---- geometry: 4 spp per thread, computed once, reused for 4 batches ----
    float w00[4], w01[4], w10[4], w11[4];
    int   li[4], gi[4];
    float dsum = 0.0f;
    const float2* __restrict__ jit2 = (const float2*)jitter;
    const int jbase = sy * SW + sx;
    const float px = -1.0f + sx * step;
    const float py = -1.0f + sy * step;

    #pragma unroll
    for (int k = 0; k < 4; ++k) {
        const int sp = q * 4 + k;
        const float2 j = jit2[sp * (SH * SW) + jbase];
        const float posx = px + j.x * step;
        const float posy = py + j.y * step;

        const float thx = fast_tanh(tt * posx);
        const float thy = fast_tanh(tt * posy);
        const float ddx = tt * (1.0f - thx * thx) * inv_s;
        const float ddy = tt * (1.0f - thy * thy) * inv_s;
        const float det = ddx * ddy;

        float gx = (thx * inv_s + 1.0f) * (WI * 0.5f) - 0.5f;
        float gy = (thy * inv_s + 1.0f) * (HI * 0.5f) - 0.5f;
        gx = fminf(fmaxf(gx, 0.0f), (float)(WI - 1));
        gy = fminf(fmaxf(gy, 0.0f), (float)(HI - 1));

        const int xb = min((int)gx, WI - 2);
        const int yb = min((int)gy, HI - 2);
        const float fx = gx - (float)xb;
        const float fy = gy - (float)yb;

        w00[k] = (1.0f - fx) * (1.0f - fy) * det;
        w01[k] = fx * (1.0f - fy) * det;
        w10[k] = (1.0f - fx) * fy * det;
        w11[k] = fx * fy * det;
        dsum  += det;
        li[k]  = (yb - y_lo) * MAXW + (xb - x_lo);
        gi[k]  = yb * WI + xb;
    }

    const size_t plane = (size_t)HI * WI;
    float acc[BATCH][CH];
    #pragma unroll
    for (int b = 0; b < BATCH; ++b)
        #pragma unroll
        for (int c = 0; c < CH; ++c) acc[b][c] = 0.0f;

    const int npix = nrows * ncols;
    const unsigned mdiv = (1u << 22) / (unsigned)ncols + 1u;  // exact: i < 2^22/ncols

    #pragma unroll 1
    for (int b = 0; b < BATCH; ++b) {
        const float* __restrict__ p0 = img + (size_t)(b * CH) * plane;
        const float* __restrict__ p1 = p0 + plane;
        const float* __restrict__ p2 = p1 + plane;

        if (fits) {
            __syncthreads();   // previous batch's sampling done before overwrite
            // ---- stage bbox -> LDS: fixed 10 iterations, fully unrolled so
            // all 30 global loads issue before the writes need them ----
            #pragma unroll
            for (int it = 0; it < 10; ++it) {
                const int idx = th + it * 256;
                const int ii  = min(idx, npix - 1);
                const int r   = (int)(((unsigned)ii * mdiv) >> 22);
                const int c   = ii - r * ncols;
                const int g   = (y_lo + r) * WI + (x_lo + c);
                union { __half2 h[2]; uint2 u; } v;
                v.h[0] = __floats2half2_rn(p0[g], p1[g]);
                v.h[1] = __floats2half2_rn(p2[g], 0.0f);
                if (idx < npix) lds[r * MAXW + c] = v.u;
            }
            __syncthreads();

            // ---- sample 4 spp from LDS ----
            #pragma unroll
            for (int k = 0; k < 4; ++k) {
                const int base = li[k];
                const uint2 q00 = lds[base];
                const uint2 q01 = lds[base + 1];
                const uint2 q10 = lds[base + MAXW];
                const uint2 q11 = lds[base + MAXW + 1];

                const float2 a00 = __half22float2(*(const __half2*)&q00.x);
                const float2 b00 = __half22float2(*(const __half2*)&q00.y);
                const float2 a01 = __half22float2(*(const __half2*)&q01.x);
                const float2 b01 = __half22float2(*(const __half2*)&q01.y);
                const float2 a10 = __half22float2(*(const __half2*)&q10.x);
                const float2 b10 = __half22float2(*(const __half2*)&q10.y);
                const float2 a11 = __half22float2(*(const __half2*)&q11.x);
                const float2 b11 = __half22float2(*(const __half2*)&q11.y);

                acc[b][0] += w00[k]*a00.x + w01[k]*a01.x + w10[k]*a10.x + w11[k]*a11.x;
                acc[b][1] += w00[k]*a00.y + w01[k]*a01.y + w10[k]*a10.y + w11[k]*a11.y;
                acc[b][2] += w00[k]*b00.x + w01[k]*b01.x + w10[k]*b10.x + w11[k]*b11.x;
            }
        } else {
            // ---- fallback: direct global gathers (never taken at t=1) ----
            #pragma unroll
            for (int k = 0; k < 4; ++k) {
                const int i0 = gi[k];
                const int i1 = i0 + WI;
                { const float2 a = *(const float2*)(p0 + i0), d = *(const float2*)(p0 + i1);
                  acc[b][0] += a.x*w00[k] + a.y*w01[k] + d.x*w10[k] + d.y*w11[k]; }
                { const float2 a = *(const float2*)(p1 + i0), d = *(const float2*)(p1 + i1);
                  acc[b][1] += a.x*w00[k] + a.y*w01[k] + d.x*w10[k] + d.y*w11[k]; }
                { const float2 a = *(const float2*)(p2 + i0), d = *(const float2*)(p2 + i1);
                  acc[b][2] += a.x*w00[k] + a.y*w01[k] + d.x*w10[k] + d.y*w11[k]; }
            }
        }
    }

    // ---- reduce spp quarters: butterfly over lane bits 4,5 ----
    #pragma unroll
    for (int m = 16; m <= 32; m <<= 1) {
        #pragma unroll
        for (int b = 0; b < BATCH; ++b)
            #pragma unroll
            for (int c = 0; c < CH; ++c)
                acc[b][c] += __shfl_xor(acc[b][c], m);
        dsum += __shfl_xor(dsum, m);
    }

    if (q == 0) {
        const float inv_d = 1.0f / dsum;
        const int pix = sy * SW + sx;
        #pragma unroll
        for (int b = 0; b < BATCH; ++b)
            #pragma unroll
            for (int c = 0; c < CH; ++c)
                out[(size_t)(b * CH + c) * (SH * SW) + pix] = acc[b][c] * inv_d;
    }
}

extern "C" void kernel_launch(void* const* d_in, const int* in_sizes, int n_in,
                              void* d_out, int out_size, void* d_ws, size_t ws_size,
                              hipStream_t stream) {
    const float* img    = (const float*)d_in[0];
    const float* t      = (const float*)d_in[1];
    const float* jitter = (const float*)d_in[2];
    float* out          = (float*)d_out;

    // 16 tx * 64 ty = 1024 blocks; 256 threads = 16 px-x * 4 spp-q * 4 px-y.
    hipLaunchKernelGGL(foveated_tile4, dim3(1024), dim3(256), 0, stream,
                       img, t, jitter, out);
}